// Round 9
// baseline (743.993 us; speedup 1.0000x reference)
//
#include <hip/hip_runtime.h>
#include <hip/hip_bf16.h>
#include <stdint.h>

typedef __bf16 bf16x8 __attribute__((ext_vector_type(8)));
typedef float  f32x4  __attribute__((ext_vector_type(4)));
using bf16 = __hip_bfloat16;

#define NNODES 8192
#define FIN    8256      // 8192 + 64
#define NCOL   192       // 128 (W1) + 64 (W2 top)
#define KT32   258       // 8256 / 32
#define BMB    128       // rows per block (4 waves x 32 rows)

// ---- workspace layout (bytes) ----
enum : size_t {
  WCT_OFF  = 0,            // bf16 wctf [258][12][64][8]  3,170,304
  CNT_OFF  = 3170304,      // int  [8192]
  OFF_OFF  = 3203072,      // int  [8193]
  CUR_OFF  = 3236096,      // int  [8192]
  DNV_OFF  = 3268864,      // f32  [8192]
  CSR_OFF  = 3301632,      // int  [262144]
  H1_OFF   = 4350208,      // bf16 [8192][128]
  HX2_OFF  = 8544512,      // f32  [8192][64]
  RU_OFF   = 10641664,     // f32  [8192][128]
  H2_OFF   = 14835968,     // bf16 [8192][64]
  YP_OFF   = 16933120,     // f32  [ksplit][8192][192]
  YP_SLICE = 6291456
};

__global__ void k_zero_i(int* p, int n) {
  int i = blockIdx.x * 256 + threadIdx.x;
  if (i < n) p[i] = 0;
}

__global__ void k_out_zero(float* out) {
  int i = blockIdx.x * 256 + threadIdx.x;
  if (i < NNODES * 64) out[i] = 0.f;   // diagnostic signature if ws too small
}

// Build B in MFMA-fragment order: wctf[((t*12+nf)*64+lane)*8+j] =
//   Wc[k = t*32 + (lane>>4)*8 + j][col = nf*16 + (lane&15)]
__global__ void k_prep_wctf(const float* __restrict__ W1, const float* __restrict__ W2,
                            bf16* __restrict__ wctf) {
  int gid = blockIdx.x * 256 + threadIdx.x;
  if (gid >= KT32 * 12 * 64) return;
  int t = gid / 768;
  int rem = gid - t * 768;
  int nf = rem >> 6, lane = rem & 63;
  int col = nf * 16 + (lane & 15);
  int k0 = t * 32 + (lane >> 4) * 8;
  union { bf16 h[8]; uint4 v; } u;
#pragma unroll
  for (int j = 0; j < 8; ++j) {
    int k = k0 + j;
    float v;
    if (col < 128)      v = W1[(size_t)k * 128 + col];
    else if (k < 8192)  v = W2[(size_t)k * 64 + (col - 128)];
    else                v = 0.f;
    u.h[j] = __float2bfloat16(v);
  }
  *(uint4*)(wctf + (size_t)gid * 8) = u.v;
}

__global__ void k_hist(const int* __restrict__ ei, int E, int* cnt) {
  int e = blockIdx.x * 256 + threadIdx.x;
  if (e < E) atomicAdd(&cnt[ei[E + e]], 1);
}

__global__ void k_scan(const int* __restrict__ cnt, int* __restrict__ offs,
                       int* __restrict__ cur, float* __restrict__ dinv) {
  __shared__ int part[256];
  int tid = threadIdx.x;
  int base = tid * 32;
  int s = 0;
#pragma unroll
  for (int j = 0; j < 32; j++) s += cnt[base + j];
  part[tid] = s;
  __syncthreads();
  for (int off = 1; off < 256; off <<= 1) {
    int a = (tid >= off) ? part[tid - off] : 0;
    __syncthreads();
    part[tid] += a;
    __syncthreads();
  }
  int run = (tid == 0) ? 0 : part[tid - 1];
  for (int j = 0; j < 32; j++) {
    int c = cnt[base + j];
    offs[base + j] = run;
    cur[base + j]  = run;
    dinv[base + j] = rsqrtf((float)(c + 1));
    run += c;
  }
  if (tid == 255) offs[NNODES] = run;
}

__global__ void k_fill(const int* __restrict__ ei, int E, int* cur, int* __restrict__ csr) {
  int e = blockIdx.x * 256 + threadIdx.x;
  if (e < E) {
    int d = ei[E + e];
    int p = atomicAdd(&cur[d], 1);
    csr[p] = ei[e];
  }
}

__device__ __forceinline__ bf16x8 pack8(float4 a, float4 b) {
  union { bf16 h[8]; bf16x8 v; } u;
  u.h[0] = __float2bfloat16(a.x); u.h[1] = __float2bfloat16(a.y);
  u.h[2] = __float2bfloat16(a.z); u.h[3] = __float2bfloat16(a.w);
  u.h[4] = __float2bfloat16(b.x); u.h[5] = __float2bfloat16(b.y);
  u.h[6] = __float2bfloat16(b.z); u.h[7] = __float2bfloat16(b.w);
  return u.v;
}

__device__ __forceinline__ void gld16(void* ldsdst, const void* gsrc) {
  __builtin_amdgcn_global_load_lds(
      (__attribute__((address_space(1))) void*)gsrc,
      (__attribute__((address_space(3))) void*)ldsdst, 16, 0, 0);
}

// ==== real GEMM: byte-identical to round 8 (passing, 155 us) ====
__global__ __launch_bounds__(256, 2) void k_gemm(const float* __restrict__ x,
                                                 const float* __restrict__ hid,
                                                 const bf16* __restrict__ wctf,
                                                 float* __restrict__ yp,
                                                 bf16* __restrict__ h1d,
                                                 float* __restrict__ hx2d,
                                                 int tpc) {
  __shared__ uint4 smA[2][1024];   // 2 x 16 KB fp32 A tile
  __shared__ uint4 smB[2][768];    // 2 x 12 KB bf16 B tile (fragment-packed)
  const int tid = threadIdx.x;
  const int lane = tid & 63, w = tid >> 6;
  const int rl = lane & 15, g = lane >> 4;
  const int m0 = blockIdx.x * BMB;
  const int chunk = blockIdx.y;
  const int t_lo = chunk * tpc;
  const int t_hi = (t_lo + tpc > KT32) ? KT32 : (t_lo + tpc);
  const int nt = t_hi - t_lo;

  const float* asx[4]; const float* ash[4];
#pragma unroll
  for (int q = 0; q < 4; ++q) {
    int u = q * 256 + tid, row = u >> 3, s = u & 7;
    int sel = (s ^ (row & 7)) << 2;
    asx[q] = x + (size_t)(m0 + row) * 8192 + sel;
    ash[q] = hid + (size_t)(m0 + row) * 64 + sel;
  }

  f32x4 acc0[12] = {};
  f32x4 acc1[12] = {};
  const int sl0 = (g * 2) ^ (rl & 7);
  const int sl1 = (g * 2 + 1) ^ (rl & 7);
  const int ra0 = (w * 32 + rl) * 8;
  const int ra1 = (w * 32 + 16 + rl) * 8;

#define STAGE(b, t) do {                                                        \
    const int _t = (t);                                                         \
    if (_t < 256) {                                                             \
      const int _k = _t * 32;                                                   \
      _Pragma("unroll")                                                         \
      for (int q = 0; q < 4; ++q) gld16(&smA[b][q * 256 + tid], asx[q] + _k);   \
    } else {                                                                    \
      const int _k = (_t - 256) * 32;                                           \
      _Pragma("unroll")                                                         \
      for (int q = 0; q < 4; ++q) gld16(&smA[b][q * 256 + tid], ash[q] + _k);   \
    }                                                                           \
    const bf16* _bt = wctf + (size_t)_t * 6144;                                 \
    _Pragma("unroll")                                                           \
    for (int q = 0; q < 3; ++q)                                                 \
      gld16(&smB[b][q * 256 + tid], _bt + (size_t)(q * 256 + tid) * 8);         \
  } while (0)

  STAGE(0, t_lo);

  for (int it = 0; it < nt; ++it) {
    const int c = it & 1;
    const bool hn = (it + 1 < nt);
    if (hn) STAGE(c ^ 1, t_lo + it + 1);

    if (hn) asm volatile("s_waitcnt vmcnt(7)" ::: "memory");
    else    asm volatile("s_waitcnt vmcnt(0)" ::: "memory");
    __builtin_amdgcn_s_barrier();
    asm volatile("" ::: "memory");

    union { uint4 u; float4 f; } a00, a01, a10, a11;
    a00.u = smA[c][ra0 + sl0]; a01.u = smA[c][ra0 + sl1];
    a10.u = smA[c][ra1 + sl0]; a11.u = smA[c][ra1 + sl1];
    bf16x8 af0 = pack8(a00.f, a01.f);
    bf16x8 af1 = pack8(a10.f, a11.f);
#pragma unroll
    for (int nf = 0; nf < 12; ++nf) {
      bf16x8 bfr = *(const bf16x8*)&smB[c][nf * 64 + lane];
      acc0[nf] = __builtin_amdgcn_mfma_f32_16x16x32_bf16(af0, bfr, acc0[nf], 0, 0, 0);
      acc1[nf] = __builtin_amdgcn_mfma_f32_16x16x32_bf16(af1, bfr, acc1[nf], 0, 0, 0);
    }
    asm volatile("" ::: "memory");
    __builtin_amdgcn_s_barrier();
    asm volatile("" ::: "memory");
  }

  if (h1d) {
#pragma unroll
    for (int nf = 0; nf < 12; ++nf) {
      int col = nf * 16 + rl;
#pragma unroll
      for (int tt = 0; tt < 4; ++tt) {
        int ra = m0 + w * 32 + g * 4 + tt;
        int rb = ra + 16;
        if (col < 128) {
          h1d[(size_t)ra * 128 + col] = __float2bfloat16(acc0[nf][tt]);
          h1d[(size_t)rb * 128 + col] = __float2bfloat16(acc1[nf][tt]);
        } else {
          hx2d[(size_t)ra * 64 + (col - 128)] = acc0[nf][tt];
          hx2d[(size_t)rb * 64 + (col - 128)] = acc1[nf][tt];
        }
      }
    }
  } else {
    float* ypc = yp + (size_t)chunk * ((size_t)NNODES * NCOL);
#pragma unroll
    for (int nf = 0; nf < 12; ++nf) {
      int col = nf * 16 + rl;
#pragma unroll
      for (int tt = 0; tt < 4; ++tt) {
        int ra = m0 + w * 32 + g * 4 + tt;
        ypc[(size_t)ra * NCOL + col] = acc0[nf][tt];
        ypc[(size_t)(ra + 16) * NCOL + col] = acc1[nf][tt];
      }
    }
  }
}
#undef STAGE

// ==== ablation probes (timing only; results to scratch) ====
// V=0: stage + vmcnt + barriers (mem+sync)   V=1: CONTIGUOUS stage + sync (DRAM probe)
// V=2: ds_read + MFMA + barriers (LDS+compute)  V=3: stage+read+MFMA, NO sync
template<int V, int REP>
__global__ __launch_bounds__(256, 2) void k_probe(const float* __restrict__ x,
                                                  const float* __restrict__ hid,
                                                  const bf16* __restrict__ wctf,
                                                  float* __restrict__ scratch,
                                                  int tpc) {
  __shared__ uint4 smA[2][1024];
  __shared__ uint4 smB[2][768];
  const int tid = threadIdx.x;
  const int lane = tid & 63, w = tid >> 6;
  const int rl = lane & 15, g = lane >> 4;
  const int m0 = blockIdx.x * BMB;
  const int chunk = blockIdx.y;
  const int t_lo = chunk * tpc;
  const int t_hi = (t_lo + tpc > KT32) ? KT32 : (t_lo + tpc);
  const int nt = t_hi - t_lo;

  const float* asx[4]; const float* ash[4];
#pragma unroll
  for (int q = 0; q < 4; ++q) {
    int u = q * 256 + tid, row = u >> 3, s = u & 7;
    int sel = (s ^ (row & 7)) << 2;
    asx[q] = x + (size_t)(m0 + row) * 8192 + sel;
    ash[q] = hid + (size_t)(m0 + row) * 64 + sel;
  }
  const uint4* xu4 = (const uint4*)x;                    // 2^24 uint4 total
  const unsigned sbase = (unsigned)(blockIdx.x + 64u * blockIdx.y) * 2097143u;

  f32x4 acc0[12] = {};
  f32x4 acc1[12] = {};
  const int sl0 = (g * 2) ^ (rl & 7);
  const int sl1 = (g * 2 + 1) ^ (rl & 7);
  const int ra0 = (w * 32 + rl) * 8;
  const int ra1 = (w * 32 + 16 + rl) * 8;

  for (int rep = 0; rep < REP; ++rep) {
    for (int it = 0; it < nt; ++it) {
      const int c = it & 1;
      const int tn = t_lo + ((it + 1 < nt) ? (it + 1) : 0);
      if constexpr (V == 0 || V == 3) {
        if (tn < 256) {
          const int _k = tn * 32;
#pragma unroll
          for (int q = 0; q < 4; ++q) gld16(&smA[c ^ 1][q * 256 + tid], asx[q] + _k);
        } else {
          const int _k = (tn - 256) * 32;
#pragma unroll
          for (int q = 0; q < 4; ++q) gld16(&smA[c ^ 1][q * 256 + tid], ash[q] + _k);
        }
        const bf16* _bt = wctf + (size_t)tn * 6144;
#pragma unroll
        for (int q = 0; q < 3; ++q)
          gld16(&smB[c ^ 1][q * 256 + tid], _bt + (size_t)(q * 256 + tid) * 8);
      } else if constexpr (V == 1) {
        unsigned base = sbase + (unsigned)(rep * nt + it) * 1792u;
#pragma unroll
        for (int q = 0; q < 4; ++q)
          gld16(&smA[c ^ 1][q * 256 + tid], &xu4[(base + (unsigned)(q * 256 + tid)) & 0xFFFFFFu]);
        const bf16* _bt = wctf + (size_t)tn * 6144;
#pragma unroll
        for (int q = 0; q < 3; ++q)
          gld16(&smB[c ^ 1][q * 256 + tid], _bt + (size_t)(q * 256 + tid) * 8);
      }
      if constexpr (V == 0 || V == 1) {
        asm volatile("s_waitcnt vmcnt(7)" ::: "memory");
      }
      if constexpr (V != 3) {
        __builtin_amdgcn_s_barrier();
        asm volatile("" ::: "memory");
      }
      if constexpr (V == 2 || V == 3) {
        union { uint4 u; float4 f; } a00, a01, a10, a11;
        a00.u = smA[c][ra0 + sl0]; a01.u = smA[c][ra0 + sl1];
        a10.u = smA[c][ra1 + sl0]; a11.u = smA[c][ra1 + sl1];
        bf16x8 af0 = pack8(a00.f, a01.f);
        bf16x8 af1 = pack8(a10.f, a11.f);
#pragma unroll
        for (int nf = 0; nf < 12; ++nf) {
          bf16x8 bfr = *(const bf16x8*)&smB[c][nf * 64 + lane];
          acc0[nf] = __builtin_amdgcn_mfma_f32_16x16x32_bf16(af0, bfr, acc0[nf], 0, 0, 0);
          acc1[nf] = __builtin_amdgcn_mfma_f32_16x16x32_bf16(af1, bfr, acc1[nf], 0, 0, 0);
        }
      }
      if constexpr (V != 3) {
        asm volatile("" ::: "memory");
        __builtin_amdgcn_s_barrier();
        asm volatile("" ::: "memory");
      }
    }
  }
  asm volatile("s_waitcnt vmcnt(0)" ::: "memory");
  if constexpr (V == 2 || V == 3) {
    f32x4 s = {};
#pragma unroll
    for (int nf = 0; nf < 12; ++nf) { s += acc0[nf]; s += acc1[nf]; }
    scratch[(size_t)(blockIdx.x + 64 * blockIdx.y) * 256 + tid] = s[0] + s[1] + s[2] + s[3];
  } else if (tid == 0) {
    scratch[blockIdx.x + 64 * blockIdx.y] = 1.f;
  }
}

// sum K-split partials; h1 -> bf16, hx2 -> fp32
__global__ void k_reduce(const float* __restrict__ yp, bf16* __restrict__ h1,
                         float* __restrict__ hx2, int nch) {
  int idx = blockIdx.x * 256 + threadIdx.x;  // < 8192*192
  float s = 0.f;
  for (int c = 0; c < nch; c++) s += yp[(size_t)c * ((size_t)NNODES * NCOL) + idx];
  int i = idx / NCOL, c = idx - i * NCOL;
  if (c < 128) h1[(size_t)i * 128 + c] = __float2bfloat16(s);
  else         hx2[(size_t)i * 64 + (c - 128)] = s;
}

__device__ __forceinline__ float bflo(unsigned v) { return __uint_as_float(v << 16); }
__device__ __forceinline__ float bfhi(unsigned v) { return __uint_as_float(v & 0xffff0000u); }

__global__ void k_scat1(const bf16* __restrict__ h1b, const int* __restrict__ offs,
                        const int* __restrict__ csr, const float* __restrict__ dinv,
                        const float* __restrict__ b1, float* __restrict__ ru) {
  int node = blockIdx.x * 4 + (threadIdx.x >> 6);
  int lane = threadIdx.x & 63;
  const unsigned* h1u = (const unsigned*)h1b;
  float dd = dinv[node];
  unsigned vv = h1u[(size_t)node * 64 + lane];
  float ax = bflo(vv) * dd * dd, ay = bfhi(vv) * dd * dd;
  int e0 = offs[node], e1 = offs[node + 1];
  for (int e = e0; e < e1; ++e) {
    int s = csr[e];
    float nrm = dinv[s] * dd;
    unsigned wv = h1u[(size_t)s * 64 + lane];
    ax += bflo(wv) * nrm;
    ay += bfhi(wv) * nrm;
  }
  ax += b1[lane * 2];
  ay += b1[lane * 2 + 1];
  ax = 1.f / (1.f + expf(-ax));
  ay = 1.f / (1.f + expf(-ay));
  ru[(size_t)node * 128 + lane * 2]     = ax;
  ru[(size_t)node * 128 + lane * 2 + 1] = ay;
}

__global__ void k_rh(const float* __restrict__ ru, const float* __restrict__ hidden,
                     const float* __restrict__ hx2, const float* __restrict__ W2,
                     bf16* __restrict__ h2) {
  __shared__ float W2s[64][64];
  __shared__ float rhs[4][64];
  int tid = threadIdx.x;
#pragma unroll
  for (int t = 0; t < 16; ++t) {
    int idx = tid + 256 * t;
    int j = idx >> 6, c = idx & 63;
    W2s[j][c] = W2[(size_t)(8192 + j) * 64 + c];
  }
  int w = tid >> 6, lane = tid & 63;
  int i = blockIdx.x * 4 + w;
  float rv = ru[(size_t)(i >> 1) * 128 + ((i & 1) << 6) + lane];
  float hv = hidden[(size_t)i * 64 + lane];
  rhs[w][lane] = rv * hv;
  __syncthreads();
  float acc = hx2[(size_t)i * 64 + lane];
#pragma unroll 8
  for (int j = 0; j < 64; ++j) acc += rhs[w][j] * W2s[j][lane];
  h2[(size_t)i * 64 + lane] = __float2bfloat16(acc);
}

__global__ void k_scat2(const bf16* __restrict__ h2b, const int* __restrict__ offs,
                        const int* __restrict__ csr, const float* __restrict__ dinv,
                        const float* __restrict__ b2, const float* __restrict__ ru,
                        const float* __restrict__ hidden, float* __restrict__ out) {
  int node = blockIdx.x * 4 + (threadIdx.x >> 6);
  int lane = threadIdx.x & 63;
  const unsigned short* h2u = (const unsigned short*)h2b;
  float dd = dinv[node];
  float acc = bflo((unsigned)h2u[(size_t)node * 64 + lane]) * dd * dd;
  int e0 = offs[node], e1 = offs[node + 1];
  for (int e = e0; e < e1; ++e) {
    int s = csr[e];
    acc += bflo((unsigned)h2u[(size_t)s * 64 + lane]) * dinv[s] * dd;
  }
  acc += b2[lane];
  float cv = tanhf(acc);
  float u = ru[(size_t)(4096 + (node >> 1)) * 128 + ((node & 1) << 6) + lane];
  float hv = hidden[(size_t)node * 64 + lane];
  out[(size_t)node * 64 + lane] = u * hv + (1.f - u) * cv;
}

extern "C" void kernel_launch(void* const* d_in, const int* in_sizes, int n_in,
                              void* d_out, int out_size, void* d_ws, size_t ws_size,
                              hipStream_t stream) {
  (void)n_in; (void)out_size;
  const float* x   = (const float*)d_in[0];
  const float* hid = (const float*)d_in[1];
  const float* W1  = (const float*)d_in[2];
  const float* b1  = (const float*)d_in[3];
  const float* W2  = (const float*)d_in[4];
  const float* b2  = (const float*)d_in[5];
  const int*   ei  = (const int*)d_in[6];
  const int E = in_sizes[6] / 2;
  float* out = (float*)d_out;

  int ksplit;
  if      (ws_size >= YP_OFF + 8ull * YP_SLICE) ksplit = 8;
  else if (ws_size >= YP_OFF + 4ull * YP_SLICE) ksplit = 4;
  else if (ws_size >= YP_OFF + 2ull * YP_SLICE) ksplit = 2;
  else if (ws_size >= YP_OFF)                   ksplit = 1;
  else {
    k_out_zero<<<dim3(NNODES * 64 / 256), dim3(256), 0, stream>>>(out);
    return;
  }
  const int tpc = (KT32 + ksplit - 1) / ksplit;

  char* ws = (char*)d_ws;
  bf16*  wctf = (bf16*)(ws + WCT_OFF);
  int*   cnt  = (int*)(ws + CNT_OFF);
  int*   offs = (int*)(ws + OFF_OFF);
  int*   cur  = (int*)(ws + CUR_OFF);
  float* dinv = (float*)(ws + DNV_OFF);
  int*   csr  = (int*)(ws + CSR_OFF);
  bf16*  h1   = (bf16*)(ws + H1_OFF);
  float* hx2  = (float*)(ws + HX2_OFF);
  float* ru   = (float*)(ws + RU_OFF);
  bf16*  h2   = (bf16*)(ws + H2_OFF);
  float* yp   = (float*)(ws + YP_OFF);

  k_zero_i<<<dim3(32), dim3(256), 0, stream>>>(cnt, NNODES);
  k_prep_wctf<<<dim3((KT32 * 12 * 64 + 255) / 256), dim3(256), 0, stream>>>(W1, W2, wctf);
  k_hist<<<dim3((E + 255) / 256), dim3(256), 0, stream>>>(ei, E, cnt);
  k_scan<<<dim3(1), dim3(256), 0, stream>>>(cnt, offs, cur, dinv);
  k_fill<<<dim3((E + 255) / 256), dim3(256), 0, stream>>>(ei, E, cur, csr);
  if (ksplit == 1) {
    k_gemm<<<dim3(NNODES / BMB, 1), dim3(256), 0, stream>>>(x, hid, wctf, nullptr, h1, hx2, tpc);
  } else {
    k_gemm<<<dim3(NNODES / BMB, ksplit), dim3(256), 0, stream>>>(x, hid, wctf, yp, nullptr, nullptr, tpc);
    k_reduce<<<dim3(NNODES * NCOL / 256), dim3(256), 0, stream>>>(yp, h1, hx2, ksplit);
  }
  k_scat1<<<dim3(NNODES / 4), dim3(256), 0, stream>>>(h1, offs, csr, dinv, b1, ru);
  k_rh<<<dim3(NNODES / 4), dim3(256), 0, stream>>>(ru, hid, hx2, W2, h2);
  k_scat2<<<dim3(NNODES / 4), dim3(256), 0, stream>>>(h2, offs, csr, dinv, b2, ru, hid, out);

  // ---- ablation probes (timing only; yp is free scratch after k_reduce) ----
  if (ksplit >= 2) {
    float* scr = yp;
    k_probe<0, 4><<<dim3(NNODES / BMB, ksplit), dim3(256), 0, stream>>>(x, hid, wctf, scr, tpc);
    k_probe<1, 4><<<dim3(NNODES / BMB, ksplit), dim3(256), 0, stream>>>(x, hid, wctf, scr, tpc);
    k_probe<2, 8><<<dim3(NNODES / BMB, ksplit), dim3(256), 0, stream>>>(x, hid, wctf, scr, tpc);
    k_probe<3, 4><<<dim3(NNODES / BMB, ksplit), dim3(256), 0, stream>>>(x, hid, wctf, scr, tpc);
  }
}

// Round 10
// 213.349 us; speedup vs baseline: 3.4872x; 3.4872x over previous
//
#include <hip/hip_runtime.h>
#include <hip/hip_bf16.h>
#include <stdint.h>

typedef __bf16 bf16x8 __attribute__((ext_vector_type(8)));
typedef float  f32x4  __attribute__((ext_vector_type(4)));
typedef unsigned uint4v __attribute__((ext_vector_type(4)));
using bf16 = __hip_bfloat16;

#define NNODES 8192
#define FIN    8256      // 8192 + 64
#define NCOL   192       // 128 (W1) + 64 (W2 top)
#define KT32   258       // 8256 / 32
#define BMB    128       // rows per block (4 waves x 32 rows)

// ---- workspace layout (bytes) ----
enum : size_t {
  WCT_OFF  = 0,            // bf16 wctf [258][12][64][8]  3,170,304
  CNT_OFF  = 3170304,      // int  [8192]
  OFF_OFF  = 3203072,      // int  [8193]
  CUR_OFF  = 3236096,      // int  [8192]
  DNV_OFF  = 3268864,      // f32  [8192]
  CSR_OFF  = 3301632,      // int  [262144]
  H1_OFF   = 4350208,      // bf16 [8192][128]
  HX2_OFF  = 8544512,      // f32  [8192][64]
  RU_OFF   = 10641664,     // f32  [8192][128]
  H2_OFF   = 14835968,     // bf16 [8192][64]
  YP_OFF   = 16933120,     // f32  [ksplit][8192][192]
  YP_SLICE = 6291456
};

__global__ void k_zero_i(int* p, int n) {
  int i = blockIdx.x * 256 + threadIdx.x;
  if (i < n) p[i] = 0;
}

__global__ void k_out_zero(float* out) {
  int i = blockIdx.x * 256 + threadIdx.x;
  if (i < NNODES * 64) out[i] = 0.f;   // diagnostic signature if ws too small
}

// Build B in MFMA-fragment order: wctf[((t*12+nf)*64+lane)*8+j] =
//   Wc[k = t*32 + (lane>>4)*8 + j][col = nf*16 + (lane&15)]
__global__ void k_prep_wctf(const float* __restrict__ W1, const float* __restrict__ W2,
                            bf16* __restrict__ wctf) {
  int gid = blockIdx.x * 256 + threadIdx.x;
  if (gid >= KT32 * 12 * 64) return;
  int t = gid / 768;
  int rem = gid - t * 768;
  int nf = rem >> 6, lane = rem & 63;
  int col = nf * 16 + (lane & 15);
  int k0 = t * 32 + (lane >> 4) * 8;
  union { bf16 h[8]; uint4 v; } u;
#pragma unroll
  for (int j = 0; j < 8; ++j) {
    int k = k0 + j;
    float v;
    if (col < 128)      v = W1[(size_t)k * 128 + col];
    else if (k < 8192)  v = W2[(size_t)k * 64 + (col - 128)];
    else                v = 0.f;
    u.h[j] = __float2bfloat16(v);
  }
  *(uint4*)(wctf + (size_t)gid * 8) = u.v;
}

__global__ void k_hist(const int* __restrict__ ei, int E, int* cnt) {
  int e = blockIdx.x * 256 + threadIdx.x;
  if (e < E) atomicAdd(&cnt[ei[E + e]], 1);
}

__global__ void k_scan(const int* __restrict__ cnt, int* __restrict__ offs,
                       int* __restrict__ cur, float* __restrict__ dinv) {
  __shared__ int part[256];
  int tid = threadIdx.x;
  int base = tid * 32;
  int s = 0;
#pragma unroll
  for (int j = 0; j < 32; j++) s += cnt[base + j];
  part[tid] = s;
  __syncthreads();
  for (int off = 1; off < 256; off <<= 1) {
    int a = (tid >= off) ? part[tid - off] : 0;
    __syncthreads();
    part[tid] += a;
    __syncthreads();
  }
  int run = (tid == 0) ? 0 : part[tid - 1];
  for (int j = 0; j < 32; j++) {
    int c = cnt[base + j];
    offs[base + j] = run;
    cur[base + j]  = run;
    dinv[base + j] = rsqrtf((float)(c + 1));
    run += c;
  }
  if (tid == 255) offs[NNODES] = run;
}

__global__ void k_fill(const int* __restrict__ ei, int E, int* cur, int* __restrict__ csr) {
  int e = blockIdx.x * 256 + threadIdx.x;
  if (e < E) {
    int d = ei[E + e];
    int p = atomicAdd(&cur[d], 1);
    csr[p] = ei[e];
  }
}

__device__ __forceinline__ bf16x8 pack8(float4 a, float4 b) {
  union { bf16 h[8]; bf16x8 v; } u;
  u.h[0] = __float2bfloat16(a.x); u.h[1] = __float2bfloat16(a.y);
  u.h[2] = __float2bfloat16(a.z); u.h[3] = __float2bfloat16(a.w);
  u.h[4] = __float2bfloat16(b.x); u.h[5] = __float2bfloat16(b.y);
  u.h[6] = __float2bfloat16(b.z); u.h[7] = __float2bfloat16(b.w);
  return u.v;
}

__device__ __forceinline__ void gld16(void* ldsdst, const void* gsrc) {
  __builtin_amdgcn_global_load_lds(
      (__attribute__((address_space(1))) void*)gsrc,
      (__attribute__((address_space(3))) void*)ldsdst, 16, 0, 0);
}

// C = [x | hidden] @ Wc : M=8192, N=192, K=8256
// Round-8 structure + H1 fix: fragment reads are inline-asm ds_read_b128 so the
// waitcnt pass cannot insert vmcnt(0) before them (it drained the prefetch every
// iter in rounds 7/8). Own lgkmcnt(0) + sched_barrier(0) per guide rule #18.
__global__ __launch_bounds__(256, 2) void k_gemm(const float* __restrict__ x,
                                                 const float* __restrict__ hid,
                                                 const bf16* __restrict__ wctf,
                                                 float* __restrict__ yp,
                                                 bf16* __restrict__ h1d,
                                                 float* __restrict__ hx2d,
                                                 int tpc) {
  __shared__ uint4 smA[2][1024];   // 2 x 16 KB fp32 A tile
  __shared__ uint4 smB[2][768];    // 2 x 12 KB bf16 B tile (fragment-packed)
  const int tid = threadIdx.x;
  const int lane = tid & 63, w = tid >> 6;
  const int rl = lane & 15, g = lane >> 4;
  const int m0 = blockIdx.x * BMB;
  const int chunk = blockIdx.y;
  const int t_lo = chunk * tpc;
  const int t_hi = (t_lo + tpc > KT32) ? KT32 : (t_lo + tpc);
  const int nt = t_hi - t_lo;

  const float* asx[4]; const float* ash[4];
#pragma unroll
  for (int q = 0; q < 4; ++q) {
    int u = q * 256 + tid, row = u >> 3, s = u & 7;
    int sel = (s ^ (row & 7)) << 2;
    asx[q] = x + (size_t)(m0 + row) * 8192 + sel;
    ash[q] = hid + (size_t)(m0 + row) * 64 + sel;
  }

  f32x4 acc0[12] = {};
  f32x4 acc1[12] = {};
  const int sl0 = (g * 2) ^ (rl & 7);
  const int sl1 = (g * 2 + 1) ^ (rl & 7);
  const int ra0 = (w * 32 + rl) * 8;
  const int ra1 = (w * 32 + 16 + rl) * 8;

  // 32-bit LDS byte addresses (buffer 0); buffer 1 = +16384 (A) / +12288 (B)
  const unsigned baseA = (unsigned)(uintptr_t)&smA[0][0];
  const unsigned baseB = (unsigned)(uintptr_t)&smB[0][0];
  const unsigned aA0 = baseA + (unsigned)(ra0 + sl0) * 16u;
  const unsigned aA1 = baseA + (unsigned)(ra0 + sl1) * 16u;
  const unsigned aA2 = baseA + (unsigned)(ra1 + sl0) * 16u;
  const unsigned aA3 = baseA + (unsigned)(ra1 + sl1) * 16u;
  const unsigned aB  = baseB + (unsigned)lane * 16u;

#define STAGE(b, t) do {                                                        \
    const int _t = (t);                                                         \
    if (_t < 256) {                                                             \
      const int _k = _t * 32;                                                   \
      _Pragma("unroll")                                                         \
      for (int q = 0; q < 4; ++q) gld16(&smA[b][q * 256 + tid], asx[q] + _k);   \
    } else {                                                                    \
      const int _k = (_t - 256) * 32;                                           \
      _Pragma("unroll")                                                         \
      for (int q = 0; q < 4; ++q) gld16(&smA[b][q * 256 + tid], ash[q] + _k);   \
    }                                                                           \
    const bf16* _bt = wctf + (size_t)_t * 6144;                                 \
    _Pragma("unroll")                                                           \
    for (int q = 0; q < 3; ++q)                                                 \
      gld16(&smB[b][q * 256 + tid], _bt + (size_t)(q * 256 + tid) * 8);         \
  } while (0)

  STAGE(0, t_lo);

  for (int it = 0; it < nt; ++it) {
    const int c = it & 1;
    const bool hn = (it + 1 < nt);
    if (hn) STAGE(c ^ 1, t_lo + it + 1);

    if (hn) asm volatile("s_waitcnt vmcnt(7)" ::: "memory");
    else    asm volatile("s_waitcnt vmcnt(0)" ::: "memory");
    __builtin_amdgcn_s_barrier();

    const unsigned offA = c ? 16384u : 0u;
    const unsigned offB = c ? 12288u : 0u;
    union { uint4v u; float4 f; bf16x8 h; } a00, a01, a10, a11, bv[12];
    asm volatile("ds_read_b128 %0, %1" : "=v"(a00.u) : "v"(aA0 + offA));
    asm volatile("ds_read_b128 %0, %1" : "=v"(a01.u) : "v"(aA1 + offA));
    asm volatile("ds_read_b128 %0, %1" : "=v"(a10.u) : "v"(aA2 + offA));
    asm volatile("ds_read_b128 %0, %1" : "=v"(a11.u) : "v"(aA3 + offA));
#pragma unroll
    for (int nf = 0; nf < 12; ++nf)
      asm volatile("ds_read_b128 %0, %1 offset:%c2"
                   : "=v"(bv[nf].u) : "v"(aB + offB), "i"(nf * 1024));
    asm volatile("s_waitcnt lgkmcnt(0)" ::: "memory");
    __builtin_amdgcn_sched_barrier(0);

    bf16x8 af0 = pack8(a00.f, a01.f);
    bf16x8 af1 = pack8(a10.f, a11.f);
#pragma unroll
    for (int nf = 0; nf < 12; ++nf) {
      acc0[nf] = __builtin_amdgcn_mfma_f32_16x16x32_bf16(af0, bv[nf].h, acc0[nf], 0, 0, 0);
      acc1[nf] = __builtin_amdgcn_mfma_f32_16x16x32_bf16(af1, bv[nf].h, acc1[nf], 0, 0, 0);
    }
    asm volatile("" ::: "memory");
    __builtin_amdgcn_s_barrier();
    asm volatile("" ::: "memory");
  }
#undef STAGE

  // C/D layout (HW-verified): col = lane&15, row = (lane>>4)*4 + reg
  if (h1d) {  // direct mode (ksplit==1)
#pragma unroll
    for (int nf = 0; nf < 12; ++nf) {
      int col = nf * 16 + rl;
#pragma unroll
      for (int tt = 0; tt < 4; ++tt) {
        int ra = m0 + w * 32 + g * 4 + tt;
        int rb = ra + 16;
        if (col < 128) {
          h1d[(size_t)ra * 128 + col] = __float2bfloat16(acc0[nf][tt]);
          h1d[(size_t)rb * 128 + col] = __float2bfloat16(acc1[nf][tt]);
        } else {
          hx2d[(size_t)ra * 64 + (col - 128)] = acc0[nf][tt];
          hx2d[(size_t)rb * 64 + (col - 128)] = acc1[nf][tt];
        }
      }
    }
  } else {
    float* ypc = yp + (size_t)chunk * ((size_t)NNODES * NCOL);
#pragma unroll
    for (int nf = 0; nf < 12; ++nf) {
      int col = nf * 16 + rl;
#pragma unroll
      for (int tt = 0; tt < 4; ++tt) {
        int ra = m0 + w * 32 + g * 4 + tt;
        ypc[(size_t)ra * NCOL + col] = acc0[nf][tt];
        ypc[(size_t)(ra + 16) * NCOL + col] = acc1[nf][tt];
      }
    }
  }
}

// sum K-split partials; h1 -> bf16, hx2 -> fp32
__global__ void k_reduce(const float* __restrict__ yp, bf16* __restrict__ h1,
                         float* __restrict__ hx2, int nch) {
  int idx = blockIdx.x * 256 + threadIdx.x;  // < 8192*192
  float s = 0.f;
  for (int c = 0; c < nch; c++) s += yp[(size_t)c * ((size_t)NNODES * NCOL) + idx];
  int i = idx / NCOL, c = idx - i * NCOL;
  if (c < 128) h1[(size_t)i * 128 + c] = __float2bfloat16(s);
  else         hx2[(size_t)i * 64 + (c - 128)] = s;
}

__device__ __forceinline__ float bflo(unsigned v) { return __uint_as_float(v << 16); }
__device__ __forceinline__ float bfhi(unsigned v) { return __uint_as_float(v & 0xffff0000u); }

__global__ void k_scat1(const bf16* __restrict__ h1b, const int* __restrict__ offs,
                        const int* __restrict__ csr, const float* __restrict__ dinv,
                        const float* __restrict__ b1, float* __restrict__ ru) {
  int node = blockIdx.x * 4 + (threadIdx.x >> 6);
  int lane = threadIdx.x & 63;
  const unsigned* h1u = (const unsigned*)h1b;
  float dd = dinv[node];
  unsigned vv = h1u[(size_t)node * 64 + lane];
  float ax = bflo(vv) * dd * dd, ay = bfhi(vv) * dd * dd;
  int e0 = offs[node], e1 = offs[node + 1];
  for (int e = e0; e < e1; ++e) {
    int s = csr[e];
    float nrm = dinv[s] * dd;
    unsigned wv = h1u[(size_t)s * 64 + lane];
    ax += bflo(wv) * nrm;
    ay += bfhi(wv) * nrm;
  }
  ax += b1[lane * 2];
  ay += b1[lane * 2 + 1];
  ax = 1.f / (1.f + expf(-ax));
  ay = 1.f / (1.f + expf(-ay));
  ru[(size_t)node * 128 + lane * 2]     = ax;
  ru[(size_t)node * 128 + lane * 2 + 1] = ay;
}

__global__ void k_rh(const float* __restrict__ ru, const float* __restrict__ hidden,
                     const float* __restrict__ hx2, const float* __restrict__ W2,
                     bf16* __restrict__ h2) {
  __shared__ float W2s[64][64];
  __shared__ float rhs[4][64];
  int tid = threadIdx.x;
#pragma unroll
  for (int t = 0; t < 16; ++t) {
    int idx = tid + 256 * t;
    int j = idx >> 6, c = idx & 63;
    W2s[j][c] = W2[(size_t)(8192 + j) * 64 + c];
  }
  int w = tid >> 6, lane = tid & 63;
  int i = blockIdx.x * 4 + w;
  float rv = ru[(size_t)(i >> 1) * 128 + ((i & 1) << 6) + lane];
  float hv = hidden[(size_t)i * 64 + lane];
  rhs[w][lane] = rv * hv;
  __syncthreads();
  float acc = hx2[(size_t)i * 64 + lane];
#pragma unroll 8
  for (int j = 0; j < 64; ++j) acc += rhs[w][j] * W2s[j][lane];
  h2[(size_t)i * 64 + lane] = __float2bfloat16(acc);
}

__global__ void k_scat2(const bf16* __restrict__ h2b, const int* __restrict__ offs,
                        const int* __restrict__ csr, const float* __restrict__ dinv,
                        const float* __restrict__ b2, const float* __restrict__ ru,
                        const float* __restrict__ hidden, float* __restrict__ out) {
  int node = blockIdx.x * 4 + (threadIdx.x >> 6);
  int lane = threadIdx.x & 63;
  const unsigned short* h2u = (const unsigned short*)h2b;
  float dd = dinv[node];
  float acc = bflo((unsigned)h2u[(size_t)node * 64 + lane]) * dd * dd;
  int e0 = offs[node], e1 = offs[node + 1];
  for (int e = e0; e < e1; ++e) {
    int s = csr[e];
    acc += bflo((unsigned)h2u[(size_t)s * 64 + lane]) * dinv[s] * dd;
  }
  acc += b2[lane];
  float cv = tanhf(acc);
  float u = ru[(size_t)(4096 + (node >> 1)) * 128 + ((node & 1) << 6) + lane];
  float hv = hidden[(size_t)node * 64 + lane];
  out[(size_t)node * 64 + lane] = u * hv + (1.f - u) * cv;
}

extern "C" void kernel_launch(void* const* d_in, const int* in_sizes, int n_in,
                              void* d_out, int out_size, void* d_ws, size_t ws_size,
                              hipStream_t stream) {
  (void)n_in; (void)out_size;
  const float* x   = (const float*)d_in[0];
  const float* hid = (const float*)d_in[1];
  const float* W1  = (const float*)d_in[2];
  const float* b1  = (const float*)d_in[3];
  const float* W2  = (const float*)d_in[4];
  const float* b2  = (const float*)d_in[5];
  const int*   ei  = (const int*)d_in[6];
  const int E = in_sizes[6] / 2;
  float* out = (float*)d_out;

  int ksplit;
  if      (ws_size >= YP_OFF + 8ull * YP_SLICE) ksplit = 8;
  else if (ws_size >= YP_OFF + 4ull * YP_SLICE) ksplit = 4;
  else if (ws_size >= YP_OFF + 2ull * YP_SLICE) ksplit = 2;
  else if (ws_size >= YP_OFF)                   ksplit = 1;
  else {
    k_out_zero<<<dim3(NNODES * 64 / 256), dim3(256), 0, stream>>>(out);
    return;
  }
  const int tpc = (KT32 + ksplit - 1) / ksplit;

  char* ws = (char*)d_ws;
  bf16*  wctf = (bf16*)(ws + WCT_OFF);
  int*   cnt  = (int*)(ws + CNT_OFF);
  int*   offs = (int*)(ws + OFF_OFF);
  int*   cur  = (int*)(ws + CUR_OFF);
  float* dinv = (float*)(ws + DNV_OFF);
  int*   csr  = (int*)(ws + CSR_OFF);
  bf16*  h1   = (bf16*)(ws + H1_OFF);
  float* hx2  = (float*)(ws + HX2_OFF);
  float* ru   = (float*)(ws + RU_OFF);
  bf16*  h2   = (bf16*)(ws + H2_OFF);
  float* yp   = (float*)(ws + YP_OFF);

  k_zero_i<<<dim3(32), dim3(256), 0, stream>>>(cnt, NNODES);
  k_prep_wctf<<<dim3((KT32 * 12 * 64 + 255) / 256), dim3(256), 0, stream>>>(W1, W2, wctf);
  k_hist<<<dim3((E + 255) / 256), dim3(256), 0, stream>>>(ei, E, cnt);
  k_scan<<<dim3(1), dim3(256), 0, stream>>>(cnt, offs, cur, dinv);
  k_fill<<<dim3((E + 255) / 256), dim3(256), 0, stream>>>(ei, E, cur, csr);
  if (ksplit == 1) {
    k_gemm<<<dim3(NNODES / BMB, 1), dim3(256), 0, stream>>>(x, hid, wctf, nullptr, h1, hx2, tpc);
  } else {
    k_gemm<<<dim3(NNODES / BMB, ksplit), dim3(256), 0, stream>>>(x, hid, wctf, yp, nullptr, nullptr, tpc);
    k_reduce<<<dim3(NNODES * NCOL / 256), dim3(256), 0, stream>>>(yp, h1, hx2, ksplit);
  }
  k_scat1<<<dim3(NNODES / 4), dim3(256), 0, stream>>>(h1, offs, csr, dinv, b1, ru);
  k_rh<<<dim3(NNODES / 4), dim3(256), 0, stream>>>(ru, hid, hx2, W2, h2);
  k_scat2<<<dim3(NNODES / 4), dim3(256), 0, stream>>>(h2, offs, csr, dinv, b2, ru, hid, out);
}